// Round 15
// baseline (94.662 us; speedup 1.0000x reference)
//
#include <hip/hip_runtime.h>
#include <stdint.h>

#define NB 8
#define NN 1024
#define NF 64
#define NT 12
#define NK 3
#define NO 64
#define NQ 768      // O*T
#define KKC 3072    // NK*NN contraction

typedef __attribute__((ext_vector_type(8))) short bf16x8;
typedef __attribute__((ext_vector_type(4))) float f32x4;

typedef const unsigned int __attribute__((address_space(1)))* gas1_t;
typedef unsigned int __attribute__((address_space(3)))* las3_t;

__device__ __forceinline__ void gload_lds16(const void* g, void* l) {
  __builtin_amdgcn_global_load_lds((gas1_t)g, (las3_t)l, 16, 0, 0);
}

__device__ __forceinline__ unsigned short f2bf(float f) {
  union { float f; unsigned int u; } v; v.f = f;
  unsigned int u = v.u;
  unsigned int r = (u + 0x7FFFu + ((u >> 16) & 1u)) >> 16;
  return (unsigned short)r;
}

// ---------------------------------------------------------------------------
// K0: thetaT[k][o][f] = bf16(theta[k][f][o])
// ---------------------------------------------------------------------------
__global__ void k0_thetaT(const float* __restrict__ theta, unsigned short* __restrict__ thT) {
  int i = blockIdx.x * 256 + threadIdx.x;
  if (i >= NK * NO * NF) return;
  int f = i & 63, o = (i >> 6) & 63, k = i >> 12;
  thT[i] = f2bf(theta[(k * NF + f) * NO + o]);
}

// ---------------------------------------------------------------------------
// K123 (fused): 2560 blocks, whole-block role split.
//   [0,512):    k23 role — Y[b][(o,t)][k*1024+m] = sum_f x*theta  (unchanged)
//   [512,2560): k1 role — A2 = bf16(cheb*att) with T14 rolling register
//     prefetch: att+cheb0+cheb1 issued before first barrier; cheb2 issued
//     under k=1's compute. No global-load latency exposed between barriers.
// __launch_bounds__(256,4) pins 4 waves/SIMD (4 blocks/CU) vs the +48 VGPR
// prefetch cost.
// ---------------------------------------------------------------------------
__global__ __launch_bounds__(256, 4) void k123(const float* __restrict__ x,
                                               const unsigned short* __restrict__ thT,
                                               unsigned short* __restrict__ Y,
                                               const float* __restrict__ cheb,
                                               const float* __restrict__ att,
                                               unsigned short* __restrict__ A2) {
  __shared__ alignas(16) char smem[33280];
  const int bid = blockIdx.x;
  const int tid = threadIdx.x;

  if (bid < 512) {
    // ---------------- k23 role: build Y ----------------
    unsigned short* Xs = (unsigned short*)smem;            // 24 KB, t-plane 2048 B
    const int mc = bid & 63;
    const int b  = bid >> 6;
    const int w = tid >> 6, l = tid & 63;
    const int lrow = l & 15, lk = l >> 4;

    const float* xb = x + ((size_t)(b * NN + mc * 16)) * (NF * NT);
#pragma unroll
    for (int u0 = 0; u0 < 2; ++u0) {
      const int u  = u0 * 256 + tid;       // 0..511
      const int m  = u >> 5;               // 0..15
      const int fp = u & 31;               // f-pair
      const float* src = xb + ((size_t)m * NF + fp * 2) * NT;
      float v[24];
#pragma unroll
      for (int i = 0; i < 6; ++i)
        *(float4*)(v + i * 4) = *(const float4*)(src + i * 4);
#pragma unroll
      for (int t = 0; t < 12; ++t) {
        unsigned int pk = (unsigned int)f2bf(v[t]) | ((unsigned int)f2bf(v[t + 12]) << 16);
        const int byte = (t * 2048 + m * 128 + fp * 4) ^ ((m & 7) << 4);
        *(unsigned int*)((char*)Xs + byte) = pk;
      }
    }
    __syncthreads();

    bf16x8 af[3][2];
#pragma unroll
    for (int ti = 0; ti < 3; ++ti) {
      const int t = w * 3 + ti;
#pragma unroll
      for (int kss = 0; kss < 2; ++kss) {
        const int byte = (t * 2048 + lrow * 128 + kss * 64 + lk * 16) ^ ((lrow & 7) << 4);
        af[ti][kss] = *(const bf16x8*)((const char*)Xs + byte);
      }
    }

    for (int k = 0; k < NK; ++k) {
      bf16x8 bb[2][4];
#pragma unroll
      for (int kss = 0; kss < 2; ++kss)
#pragma unroll
        for (int oj = 0; oj < 4; ++oj)
          bb[kss][oj] = *(const bf16x8*)(thT + (size_t)(k * NO + oj * 16 + lrow) * NF + kss * 32 + lk * 8);
#pragma unroll
      for (int ti = 0; ti < 3; ++ti) {
        const int t = w * 3 + ti;
        f32x4 acc[4] = {};
#pragma unroll
        for (int kss = 0; kss < 2; ++kss)
#pragma unroll
          for (int oj = 0; oj < 4; ++oj)
            acc[oj] = __builtin_amdgcn_mfma_f32_16x16x32_bf16(af[ti][kss], bb[kss][oj], acc[oj], 0, 0, 0);
#pragma unroll
        for (int oj = 0; oj < 4; ++oj) {
          const int o  = oj * 16 + lrow;
          const int mg = mc * 16 + lk * 4;
          uint2 u;
          u.x = (unsigned int)f2bf(acc[oj][0]) | ((unsigned int)f2bf(acc[oj][1]) << 16);
          u.y = (unsigned int)f2bf(acc[oj][2]) | ((unsigned int)f2bf(acc[oj][3]) << 16);
          size_t el = ((size_t)(b * NQ + o * NT + t)) * KKC + k * NN + mg;
          *(uint2*)(void*)(Y + el) = u;
        }
      }
    }
  } else {
    // ---------------- k1 role: build A2 (T14 rolling prefetch) ----------------
    float (*att_s)[65]  = (float(*)[65])smem;                 // 16640 B
    float (*cheb_s)[65] = (float(*)[65])(smem + 16640);       // 16640 B
    const int bid2 = bid - 512;          // 0..2047
    const int n0 = (bid2 & 15) * 64;
    const int m0 = ((bid2 >> 4) & 15) * 64;
    const int b  = bid2 >> 8;
    const int r4 = tid >> 4;             // 0..15
    const int c  = tid & 15;

    // issue att + cheb0 + cheb1 (12 independent float4 loads, all in flight)
    float4 attv[4], chA[4], chB[4];
#pragma unroll
    for (int p = 0; p < 4; ++p) {
      const int r = r4 + p * 16;
      attv[p] = *(const float4*)(att + ((size_t)(b * NN + m0 + r)) * NN + n0 + c * 4);
    }
#pragma unroll
    for (int p = 0; p < 4; ++p) {
      const int r = r4 + p * 16;
      chA[p] = *(const float4*)(cheb + ((size_t)(0 * NN + m0 + r)) * NN + n0 + c * 4);
    }
#pragma unroll
    for (int p = 0; p < 4; ++p) {
      const int r = r4 + p * 16;
      chB[p] = *(const float4*)(cheb + ((size_t)(1 * NN + m0 + r)) * NN + n0 + c * 4);
    }

    for (int k = 0; k < NK; ++k) {
      if (k) __syncthreads();            // prev k's cheb_s reads done
      if (k == 0) {
        // write att + cheb0
#pragma unroll
        for (int p = 0; p < 4; ++p) {
          const int r = r4 + p * 16;
          att_s[r][c * 4 + 0] = attv[p].x; att_s[r][c * 4 + 1] = attv[p].y;
          att_s[r][c * 4 + 2] = attv[p].z; att_s[r][c * 4 + 3] = attv[p].w;
          cheb_s[r][c * 4 + 0] = chA[p].x; cheb_s[r][c * 4 + 1] = chA[p].y;
          cheb_s[r][c * 4 + 2] = chA[p].z; cheb_s[r][c * 4 + 3] = chA[p].w;
        }
      } else if (k == 1) {
        // write cheb1; issue cheb2 into chA (consumed next phase)
#pragma unroll
        for (int p = 0; p < 4; ++p) {
          const int r = r4 + p * 16;
          cheb_s[r][c * 4 + 0] = chB[p].x; cheb_s[r][c * 4 + 1] = chB[p].y;
          cheb_s[r][c * 4 + 2] = chB[p].z; cheb_s[r][c * 4 + 3] = chB[p].w;
        }
#pragma unroll
        for (int p = 0; p < 4; ++p) {
          const int r = r4 + p * 16;
          chA[p] = *(const float4*)(cheb + ((size_t)(2 * NN + m0 + r)) * NN + n0 + c * 4);
        }
      } else {
        // write cheb2 (arrived during k=1 compute)
#pragma unroll
        for (int p = 0; p < 4; ++p) {
          const int r = r4 + p * 16;
          cheb_s[r][c * 4 + 0] = chA[p].x; cheb_s[r][c * 4 + 1] = chA[p].y;
          cheb_s[r][c * 4 + 2] = chA[p].z; cheb_s[r][c * 4 + 3] = chA[p].w;
        }
      }
      __syncthreads();                   // tile ready
#pragma unroll
      for (int p = 0; p < 8; ++p) {
        int e  = p * 256 + tid;
        int jn = e >> 5;
        int q  = e & 31;
        float f0 = att_s[2 * q][jn]     * cheb_s[2 * q][jn];
        float f1 = att_s[2 * q + 1][jn] * cheb_s[2 * q + 1][jn];
        unsigned int pk = (unsigned int)f2bf(f0) | ((unsigned int)f2bf(f1) << 16);
        size_t el = ((size_t)(b * NN + n0 + jn)) * KKC + k * NN + m0 + 2 * q;
        *(unsigned int*)(A2 + el) = pk;
      }
    }
  }
}

// ---------------------------------------------------------------------------
// K4: out[b][n][q] = relu( A2[b] @ Y[b]^T ), 64x128 tile, BK=64 — r3-exact
// (measured decomposition floor: ~53 µs = 906 MB staged / ~17 TB/s multi-
// block L2/L3 delivery; 8 structural variants all >= this).
// ---------------------------------------------------------------------------
__global__ __launch_bounds__(256) void k4_main(const unsigned short* __restrict__ A2,
                                               const unsigned short* __restrict__ Y,
                                               float* __restrict__ out) {
  __shared__ unsigned short Asl[64 * 64];    //  8 KB
  __shared__ unsigned short Bsl[128 * 64];   // 16 KB
  const int tid = threadIdx.x;
  const int w = tid >> 6, l = tid & 63;
  const int lrow = l & 15, lk = l >> 4;
  const int wm = w >> 1, wq = w & 1;

  const int lin = (blockIdx.x & 7) * 96 + (blockIdx.x >> 3);
  const int b   = lin / 96;
  const int rem = lin % 96;
  const int bn  = rem / 6;
  const int bq  = rem % 6;

  const unsigned short* Abase = A2 + ((size_t)(b * NN + bn * 64)) * KKC;
  const unsigned short* Bbase = Y  + ((size_t)(b * NQ + bq * 128)) * KKC;

  f32x4 acc[2][4] = {};

  for (int kt = 0; kt < KKC / 64; ++kt) {
    const int kb = kt * 64;
#pragma unroll
    for (int it = 0; it < 2; ++it) {
      const int idx = it * 256 + tid;
      const int r   = idx >> 3;
      const int c16 = (idx & 7) ^ (r & 7);
      gload_lds16(Abase + (size_t)r * KKC + kb + c16 * 8, Asl + (size_t)idx * 8);
    }
#pragma unroll
    for (int it = 0; it < 4; ++it) {
      const int idx = it * 256 + tid;
      const int r   = idx >> 3;
      const int c16 = (idx & 7) ^ (r & 7);
      gload_lds16(Bbase + (size_t)r * KKC + kb + c16 * 8, Bsl + (size_t)idx * 8);
    }
    __syncthreads();
#pragma unroll
    for (int kss = 0; kss < 2; ++kss) {
      bf16x8 af[2], bfr[4];
#pragma unroll
      for (int mi = 0; mi < 2; ++mi) {
        const int row = wm * 32 + mi * 16 + lrow;
        const int sw = (row * 128 + kss * 64 + lk * 16) ^ ((row & 7) << 4);
        af[mi] = *(const bf16x8*)((const char*)Asl + sw);
      }
#pragma unroll
      for (int nj = 0; nj < 4; ++nj) {
        const int row = wq * 64 + nj * 16 + lrow;
        const int sw = (row * 128 + kss * 64 + lk * 16) ^ ((row & 7) << 4);
        bfr[nj] = *(const bf16x8*)((const char*)Bsl + sw);
      }
#pragma unroll
      for (int mi = 0; mi < 2; ++mi)
#pragma unroll
        for (int nj = 0; nj < 4; ++nj)
          acc[mi][nj] = __builtin_amdgcn_mfma_f32_16x16x32_bf16(af[mi], bfr[nj], acc[mi][nj], 0, 0, 0);
    }
    __syncthreads();
  }

  const int nb0 = bn * 64 + wm * 32;
  const int qb0 = bq * 128 + wq * 64;
#pragma unroll
  for (int mi = 0; mi < 2; ++mi) {
#pragma unroll
    for (int nj = 0; nj < 4; ++nj) {
      const int q = qb0 + nj * 16 + lrow;
#pragma unroll
      for (int j = 0; j < 4; ++j) {
        const int n = nb0 + mi * 16 + lk * 4 + j;
        float v = acc[mi][nj][j];
        out[((size_t)(b * NN + n)) * NQ + q] = v > 0.f ? v : 0.f;
      }
    }
  }
}

// ---------------------------------------------------------------------------
extern "C" void kernel_launch(void* const* d_in, const int* in_sizes, int n_in,
                              void* d_out, int out_size, void* d_ws, size_t ws_size,
                              hipStream_t stream) {
  const float* x     = (const float*)d_in[0];   // (B,N,F,T)
  const float* att   = (const float*)d_in[1];   // (B,N,N)
  const float* cheb  = (const float*)d_in[2];   // (K,N,N)
  const float* theta = (const float*)d_in[3];   // (K,F,O)
  float* out = (float*)d_out;

  char* ws = (char*)d_ws;
  unsigned short* A2  = (unsigned short*)(ws);                 // 50,331,648 B
  unsigned short* Y   = (unsigned short*)(ws + 50331648);      // 37,748,736 B
  unsigned short* thT = (unsigned short*)(ws + 88080384);      //     24,576 B

  k0_thetaT<<<48, 256, 0, stream>>>(theta, thT);
  k123<<<2560, 256, 0, stream>>>(x, thT, Y, cheb, att, A2);
  k4_main<<<768, 256, 0, stream>>>(A2, Y, out);
}